// Round 5
// baseline (47.739 us; speedup 1.0000x reference)
//
#include <hip/hip_runtime.h>

#define BB 32
#define NN 1024
#define TT 4096
#define CC 384
#define C4 (CC/4)     // 96 float4 per row
#define RPB 128       // output rows per block
#define BPB (TT/RPB)  // 32 blocks per batch
#define THR 512

typedef float f4v __attribute__((ext_vector_type(4)));

// Fused: per-block redundant scan (2 durations/thread), LDS span-scatter for
// row->source mapping (no binary search), streamed gather + mask, NT stores.
__global__ __launch_bounds__(THR) void lr_fused(const int* __restrict__ duration,
                                                const float4* __restrict__ x4,
                                                float4* __restrict__ out4,
                                                float* __restrict__ mask) {
    __shared__ int cum[NN];
    __shared__ int wsum[8];
    __shared__ int ridx[RPB];

    const int b    = blockIdx.x >> 5;        // / BPB
    const int rblk = blockIdx.x & (BPB - 1);
    const int tid  = threadIdx.x;
    const int lane = tid & 63;
    const int wid  = tid >> 6;               // 0..7

    // ---- load 2 durations/thread, clamp
    const int2 dv = ((const int2*)(duration + b * NN))[tid];
    int d0 = max(dv.x, 0), d1 = max(dv.y, 0);
    int ps = d0 + d1;

    // wave inclusive scan of per-thread sums
    int v = ps;
    #pragma unroll
    for (int off = 1; off < 64; off <<= 1) {
        int t = __shfl_up(v, off, 64);
        if (lane >= off) v += t;
    }
    if (lane == 63) wsum[wid] = v;
    __syncthreads();
    int woff = 0, tot = 0;
    #pragma unroll
    for (int w = 0; w < 8; ++w) {
        int s = wsum[w];
        tot += s;
        if (w < wid) woff += s;
    }
    const int excl = woff + (v - ps);        // global exclusive prefix
    ((int2*)cum)[tid] = make_int2(excl + d0, excl + d0 + d1);

    const int lo = rblk * RPB;               // block's output-row window
    if (tid < RPB) {
        ridx[tid] = -1;
        mask[(size_t)b * TT + lo + tid] = (lo + tid < tot) ? 1.0f : 0.0f;
    }
    __syncthreads();

    // ---- span scatter: row n covers t in [cum[n-1], cum[n])
    {
        const int hi = lo + RPB;
        int s0 = excl, e0 = excl + d0;       // source row 2*tid
        int a = max(s0, lo), e = min(e0, hi);
        for (int t = a; t < e; ++t) ridx[t - lo] = 2 * tid;
        int s1 = e0, e1 = e0 + d1;           // source row 2*tid+1
        a = max(s1, lo); e = min(e1, hi);
        for (int t = a; t < e; ++t) ridx[t - lo] = 2 * tid + 1;
    }
    __syncthreads();

    // ---- streamed gather: 128 rows x 96 float4 = 24 iters/thread
    const float4* xb = x4 + (size_t)b * NN * C4;
    float4* ob = out4 + ((size_t)b * TT + lo) * C4;
    #pragma unroll 4
    for (int it = 0; it < RPB * C4 / THR; ++it) {
        int i = it * THR + tid;
        int r = i / C4;                      // magic-mul
        int l2 = i - r * C4;
        int id = ridx[r];
        float4 vv = make_float4(0.f, 0.f, 0.f, 0.f);
        if (id >= 0) vv = xb[(size_t)id * C4 + l2];
        __builtin_nontemporal_store(*(const f4v*)&vv, (f4v*)&ob[i]);
    }
}

extern "C" void kernel_launch(void* const* d_in, const int* in_sizes, int n_in,
                              void* d_out, int out_size, void* d_ws, size_t ws_size,
                              hipStream_t stream) {
    const float* x        = (const float*)d_in[0];
    const int*   duration = (const int*)d_in[1];
    // d_in[2] = max_length (4096) — fixed, baked into TT.

    float* out  = (float*)d_out;                    // BB*TT*CC floats
    float* mask = out + (size_t)BB * TT * CC;       // BB*TT floats

    lr_fused<<<BB * BPB, THR, 0, stream>>>(duration, (const float4*)x,
                                           (float4*)out, mask);
}

// Round 6
// 42.881 us; speedup vs baseline: 1.1133x; 1.1133x over previous
//
#include <hip/hip_runtime.h>

#define BB 32
#define NN 1024
#define TT 4096
#define CC 384
#define C4 (CC/4)    // 96 float4 per row
#define RPB 64       // output rows per block
#define BPB (TT/RPB) // 64 blocks per batch
#define THR 256

typedef float f4v __attribute__((ext_vector_type(4)));

// Fused: per-block redundant scan, binary-search row->source map, branchless
// streamed gather (always-load + mask multiply), NT stores.
__global__ __launch_bounds__(THR) void lr_fused(const int* __restrict__ duration,
                                                const float4* __restrict__ x4,
                                                float4* __restrict__ out4,
                                                float* __restrict__ mask) {
    __shared__ int cum[NN];
    __shared__ int wtot[4];
    __shared__ int ridx[RPB];

    const int b    = blockIdx.x >> 6;        // / BPB
    const int rblk = blockIdx.x & (BPB - 1);
    const int tid  = threadIdx.x;
    const int lane = tid & 63;
    const int wid  = tid >> 6;

    // ---- load 4 durations/thread, clamp, local prefix
    const int4 dv = ((const int4*)(duration + b * NN))[tid];
    int d0 = max(dv.x, 0), d1 = max(dv.y, 0), d2 = max(dv.z, 0), d3 = max(dv.w, 0);
    int p0 = d0, p1 = p0 + d1, p2 = p1 + d2, p3 = p2 + d3;

    // wave inclusive scan of thread sums
    int v = p3;
    #pragma unroll
    for (int off = 1; off < 64; off <<= 1) {
        int t = __shfl_up(v, off, 64);
        if (lane >= off) v += t;
    }
    if (lane == 63) wtot[wid] = v;
    __syncthreads();
    int woff = 0;
    #pragma unroll
    for (int w = 0; w < 4; ++w)
        if (w < wid) woff += wtot[w];
    int excl = woff + (v - p3);
    ((int4*)cum)[tid] = make_int4(excl + p0, excl + p1, excl + p2, excl + p3);
    __syncthreads();

    const int total = cum[NN - 1];

    // ---- per-row source index via binary search (first 64 threads)
    if (tid < RPB) {
        int row = rblk * RPB + tid;
        int id = -1;
        if (row < total) {
            int lo = 0, hi = NN - 1;
            #pragma unroll
            for (int it = 0; it < 10; ++it) {
                int mid = (lo + hi) >> 1;
                if (cum[mid] > row) hi = mid; else lo = mid + 1;
            }
            id = hi;
        }
        ridx[tid] = id;
        mask[(size_t)b * TT + row] = (id >= 0) ? 1.0f : 0.0f;
    }
    __syncthreads();

    // ---- branchless streamed gather: 64 rows x 96 float4 = 24 iters/thread
    const float4* xb = x4 + (size_t)b * NN * C4;
    float4* ob = out4 + ((size_t)b * TT + (size_t)rblk * RPB) * C4;
    #pragma unroll
    for (int it = 0; it < RPB * C4 / THR; ++it) {
        int i = it * THR + tid;
        int r = i / C4;                      // magic-mul
        int l2 = i - r * C4;
        int id = ridx[r];
        float m = (id >= 0) ? 1.0f : 0.0f;   // cndmask, no branch
        int idc = max(id, 0);
        float4 vv = xb[(size_t)idc * C4 + l2];  // always issued
        f4v o;
        o.x = vv.x * m; o.y = vv.y * m; o.z = vv.z * m; o.w = vv.w * m;
        __builtin_nontemporal_store(o, (f4v*)&ob[i]);
    }
}

extern "C" void kernel_launch(void* const* d_in, const int* in_sizes, int n_in,
                              void* d_out, int out_size, void* d_ws, size_t ws_size,
                              hipStream_t stream) {
    const float* x        = (const float*)d_in[0];
    const int*   duration = (const int*)d_in[1];
    // d_in[2] = max_length (4096) — fixed, baked into TT.

    float* out  = (float*)d_out;                    // BB*TT*CC floats
    float* mask = out + (size_t)BB * TT * CC;       // BB*TT floats

    lr_fused<<<BB * BPB, THR, 0, stream>>>(duration, (const float4*)x,
                                           (float4*)out, mask);
}